// Round 6
// baseline (56349.658 us; speedup 1.0000x reference)
//
#include <hip/hip_runtime.h>
#include <hip/hip_fp16.h>

// LSTM (S=16384, I=64, H=1024) -> ReLU -> FC(1024->128) -> ReLU -> FC(128->1), last step only.
// R6: critical-path surgery. R1-R5 invariance diagnosis: per-step x-prefetch stalled a wave
// on vmcnt(0) (global->LDS same iteration) and __syncthreads serialized it into every step;
// plus 2 barriers + gs LDS round-trip between h-arrival and publish. Fixes:
//  - depth-2 register pipeline for x (write landed x_{t+1}, issue x_{t+2})
//  - wave owns 2 h-indices x all 4 gates -> lane0 does activations + publish right after
//    the in-wave reduction: no barrier before publish, no gs array
//  - ONE __syncthreads per step (LDS h double-buffered; tag chain bounds skew < 2 steps)
//  - weight stream (fp16-packed, 64 dwords/lane) prefetched during the poll window,
//    asm-pinned so it cannot sink past the poll
// Sync: 8-B self-validating words (tag32<<32 | half2 payload), relaxed agent atomics.

#define S_LEN 16384
#define I_DIM 64
#define H_DIM 1024
#define NBLK  64
#define NTHR  512

typedef _Float16 half2_t __attribute__((ext_vector_type(2)));

__device__ __forceinline__ float sigmoidf_(float x) { return 1.0f / (1.0f + __expf(-x)); }
__device__ __forceinline__ float tanh_fast(float x) { return 1.0f - 2.0f / (__expf(2.0f * x) + 1.0f); }
__device__ __forceinline__ unsigned pack2(float a, float b) {
    return (unsigned)__half_as_ushort(__float2half(a)) |
           ((unsigned)__half_as_ushort(__float2half(b)) << 16);
}
__device__ __forceinline__ half2_t as_h2(unsigned u) { return __builtin_bit_cast(half2_t, u); }

// Block b owns h-indices 16b..16b+15. Wave w (0..7) owns h-indices 16b+2w+{0,1} for all
// 4 gates: 8 rows r(g,e) = g*1024 + 16b + 2w + e, local acc index 2g+e. Lane c covers
// h-cols {s*256+4c..+3}, s=0..3 (8-B LDS reads, 2-way aliasing = free).
__global__ __launch_bounds__(NTHR, 2) void lstm_persistent(
    const float* __restrict__ xseq,   // [S, 64]
    const float* __restrict__ W_ih,   // [4096, 64]
    const float* __restrict__ W_hh,   // [4096, 1024]
    const float* __restrict__ b_ih,   // [4096]
    const float* __restrict__ b_hh,   // [4096]
    unsigned long long* __restrict__ pairs)  // [2][512] (tag32<<32 | half2 payload)
{
    const int b   = blockIdx.x;
    const int tid = threadIdx.x;
    const int w   = tid >> 6;        // wave id 0..7
    const int c   = tid & 63;        // lane id

    __shared__ unsigned h_stage[2][H_DIM / 2];  // packed half2, double-buffered
    __shared__ float    x_stage[2][I_DIM];

    // ---- init: row bases, x-side weights, biases, cell state ----
    const float* wbase[8];
    float wi[8], bias[8];
    #pragma unroll
    for (int r = 0; r < 8; ++r) {
        const int grow = (r >> 1) * H_DIM + 16 * b + 2 * w + (r & 1);
        wbase[r] = W_hh + (size_t)grow * H_DIM;
        wi[r]    = W_ih[(size_t)grow * I_DIM + c];
        bias[r]  = b_ih[grow] + b_hh[grow];
    }
    float cst0 = 0.f, cst1 = 0.f;    // cell state (lane 0 of each wave)

    h_stage[0][tid] = 0u;            // h_{-1} = 0
    if (tid < 16) ((float4*)x_stage[0])[tid] = ((const float4*)xseq)[tid];
    float4 xcur = make_float4(0.f, 0.f, 0.f, 0.f);
    if (w == 7 && c < 16) xcur = ((const float4*)(xseq + (size_t)1 * I_DIM))[c];  // x_1

    // ---- initial weight fetch for t=0 (fp16-packed, 64 dwords/lane) ----
    unsigned wreg[8][8];
    #pragma unroll
    for (int r = 0; r < 8; ++r) {
        const float4* b4 = (const float4*)wbase[r];
        #pragma unroll
        for (int s = 0; s < 4; ++s) {
            const float4 f = b4[s * 64 + c];
            wreg[r][2 * s]     = pack2(f.x, f.y);
            wreg[r][2 * s + 1] = pack2(f.z, f.w);
        }
    }
    __syncthreads();

    for (int t = 0; t < S_LEN; ++t) {
        // ---- dot: W_hh . h_{t-1} (fdot2) + W_ih . x_t ----
        float acc[8] = {0.f, 0.f, 0.f, 0.f, 0.f, 0.f, 0.f, 0.f};
        #pragma unroll
        for (int s = 0; s < 4; ++s) {
            const uint2 hv = *(const uint2*)&h_stage[t & 1][s * 128 + 2 * c];  // ds_read_b64
            const half2_t ha = as_h2(hv.x), hb = as_h2(hv.y);
            #pragma unroll
            for (int r = 0; r < 8; ++r) {
                acc[r] = __builtin_amdgcn_fdot2(as_h2(wreg[r][2 * s]),     ha, acc[r], false);
                acc[r] = __builtin_amdgcn_fdot2(as_h2(wreg[r][2 * s + 1]), hb, acc[r], false);
            }
        }
        {
            const float xv = x_stage[t & 1][c];
            #pragma unroll
            for (int r = 0; r < 8; ++r) acc[r] = fmaf(wi[r], xv, acc[r]);
        }
        // in-wave butterfly reduction (all 8 rows)
        #pragma unroll
        for (int r = 0; r < 8; ++r) {
            #pragma unroll
            for (int off = 32; off > 0; off >>= 1)
                acc[r] += __shfl_xor(acc[r], off, 64);
        }

        // ---- lane 0: activations for both h-indices + publish (no barrier needed) ----
        if (c == 0) {
            const float i0 = sigmoidf_(acc[0] + bias[0]);
            const float f0 = sigmoidf_(acc[2] + bias[2]);
            const float g0 = tanh_fast(acc[4] + bias[4]);
            const float o0 = sigmoidf_(acc[6] + bias[6]);
            cst0 = f0 * cst0 + i0 * g0;
            const float h0 = o0 * tanh_fast(cst0);
            const float i1 = sigmoidf_(acc[1] + bias[1]);
            const float f1 = sigmoidf_(acc[3] + bias[3]);
            const float g1 = tanh_fast(acc[5] + bias[5]);
            const float o1 = sigmoidf_(acc[7] + bias[7]);
            cst1 = f1 * cst1 + i1 * g1;
            const float h1 = o1 * tanh_fast(cst1);
            const unsigned lo = pack2(h0, h1);
            const unsigned long long pk =
                ((unsigned long long)(unsigned)(t + 1) << 32) | (unsigned long long)lo;
            __hip_atomic_store(&pairs[(size_t)(t & 1) * (H_DIM / 2) + 8 * b + w], pk,
                               __ATOMIC_RELAXED, __HIP_MEMORY_SCOPE_AGENT);
            h_stage[(t + 1) & 1][8 * b + w] = lo;   // own-slice local fanout
        }

        // ---- x register pipeline: write landed x_{t+1}, issue x_{t+2} ----
        if (w == 7 && c < 16) {
            if (t + 1 < S_LEN) ((float4*)x_stage[(t + 1) & 1])[c] = xcur;
            const int tn = (t + 2 < S_LEN) ? t + 2 : S_LEN - 1;
            xcur = ((const float4*)(xseq + (size_t)tn * I_DIM))[c];
        }

        if (t == S_LEN - 1) break;   // last h published; nothing left to read

        // ---- prefetch next iteration's weight stream (hidden under the poll) ----
        #pragma unroll
        for (int r = 0; r < 8; ++r) {
            const float4* b4 = (const float4*)wbase[r];
            #pragma unroll
            for (int s = 0; s < 4; ++s) {
                const float4 f = b4[s * 64 + c];
                wreg[r][2 * s]     = pack2(f.x, f.y);
                wreg[r][2 * s + 1] = pack2(f.z, f.w);
            }
        }
        #pragma unroll
        for (int r = 0; r < 8; ++r)
            asm volatile("" : "+v"(wreg[r][0]), "+v"(wreg[r][1]), "+v"(wreg[r][2]),
                              "+v"(wreg[r][3]), "+v"(wreg[r][4]), "+v"(wreg[r][5]),
                              "+v"(wreg[r][6]), "+v"(wreg[r][7]));

        // ---- poll: thread tid waits on word tid (skip own block's 8 words) ----
        if ((tid >> 3) != b) {
            const unsigned tag = (unsigned)(t + 1);
            const unsigned long long* P = pairs + (size_t)(t & 1) * (H_DIM / 2);
            unsigned long long v;
            for (;;) {
                v = __hip_atomic_load(P + tid, __ATOMIC_RELAXED, __HIP_MEMORY_SCOPE_AGENT);
                if ((unsigned)(v >> 32) == tag) break;
                __builtin_amdgcn_s_sleep(1);
            }
            h_stage[(t + 1) & 1][tid] = (unsigned)v;
        }
        __syncthreads();   // the ONLY barrier per step
    }
}

// Final head: out = fc2( relu( fc1( relu(h_{S-1}) ) ) ). h_{S-1} is in pairs slot 1
// ((S-1)&1), 8-B words: low dword = half2 payload. Kernel boundary orders the reads.
__global__ __launch_bounds__(256) void fc_head(
    const unsigned long long* __restrict__ pairs,
    const float* __restrict__ fc1_w,  // [128, 1024]
    const float* __restrict__ fc1_b,  // [128]
    const float* __restrict__ fc2_w,  // [128]
    const float* __restrict__ fc2_b,  // [1]
    float* __restrict__ out)
{
    const int tid = threadIdx.x;
    __shared__ float4 hr4[H_DIM / 4];
    __shared__ float  partial[256];
    __shared__ float  r1[128];

    // words {2tid, 2tid+1} of slot 1: pa.x / pa.z are half2 payloads (pa.y/pa.w tags)
    const uint4 pa = ((const uint4*)pairs)[256 + tid];
    float4 hv = make_float4(__half2float(__ushort_as_half((unsigned short)(pa.x & 0xFFFFu))),
                            __half2float(__ushort_as_half((unsigned short)(pa.x >> 16))),
                            __half2float(__ushort_as_half((unsigned short)(pa.z & 0xFFFFu))),
                            __half2float(__ushort_as_half((unsigned short)(pa.z >> 16))));
    hv.x = fmaxf(hv.x, 0.f); hv.y = fmaxf(hv.y, 0.f);
    hv.z = fmaxf(hv.z, 0.f); hv.w = fmaxf(hv.w, 0.f);
    hr4[tid] = hv;
    __syncthreads();

    const int row = tid & 127, half = tid >> 7;
    const float4* wrow = (const float4*)(fc1_w + (size_t)row * H_DIM) + half * 128;
    float a0 = 0.f, a1 = 0.f;
    #pragma unroll 4
    for (int i = 0; i < 128; i += 2) {
        const float4 w0 = wrow[i],     h0 = hr4[half * 128 + i];
        const float4 w1 = wrow[i + 1], h1 = hr4[half * 128 + i + 1];
        a0 += w0.x * h0.x + w0.y * h0.y + w0.z * h0.z + w0.w * h0.w;
        a1 += w1.x * h1.x + w1.y * h1.y + w1.z * h1.z + w1.w * h1.w;
    }
    partial[tid] = a0 + a1;
    __syncthreads();
    if (tid < 128) {
        const float s = partial[tid] + partial[tid + 128] + fc1_b[tid];
        r1[tid] = fmaxf(s, 0.f);
    }
    __syncthreads();
    if (tid < 64) {
        float v = r1[tid] * fc2_w[tid] + r1[tid + 64] * fc2_w[tid + 64];
        #pragma unroll
        for (int off = 32; off > 0; off >>= 1) v += __shfl_xor(v, off, 64);
        if (tid == 0) out[0] = v + fc2_b[0];
    }
}

extern "C" void kernel_launch(void* const* d_in, const int* in_sizes, int n_in,
                              void* d_out, int out_size, void* d_ws, size_t ws_size,
                              hipStream_t stream) {
    (void)in_sizes; (void)n_in; (void)out_size; (void)ws_size;
    const float* xseq  = (const float*)d_in[0];
    const float* W_ih  = (const float*)d_in[1];
    const float* W_hh  = (const float*)d_in[2];
    const float* b_ih  = (const float*)d_in[3];
    const float* b_hh  = (const float*)d_in[4];
    const float* fc1_w = (const float*)d_in[5];
    const float* fc1_b = (const float*)d_in[6];
    const float* fc2_w = (const float*)d_in[7];
    const float* fc2_b = (const float*)d_in[8];
    unsigned long long* pairs = (unsigned long long*)d_ws;

    lstm_persistent<<<NBLK, NTHR, 0, stream>>>(xseq, W_ih, W_hh, b_ih, b_hh, pairs);
    fc_head<<<1, 256, 0, stream>>>(pairs, fc1_w, fc1_b, fc2_w, fc2_b, (float*)d_out);
}